// Round 1
// baseline (283.685 us; speedup 1.0000x reference)
//
#include <hip/hip_runtime.h>
#include <cstdint>

#define M_DIM 65536
#define N_DIM 512
#define K_DIM 512
#define BM 128
#define BN 128
#define BK 32
#define KSTEPS (K_DIM / BK)

typedef float f32x4 __attribute__((ext_vector_type(4)));
typedef __bf16 bf16x8 __attribute__((ext_vector_type(8)));
typedef unsigned short us8 __attribute__((ext_vector_type(8)));

__device__ __forceinline__ unsigned short f2bf(float f) {
  unsigned int u = __builtin_bit_cast(unsigned int, f);
  u += 0x7fffu + ((u >> 16) & 1u);  // round-to-nearest-even
  return (unsigned short)(u >> 16);
}

// packed f32x2 -> bf16x2 (RNE), 1 VALU op for 2 elements
__device__ __forceinline__ unsigned int cvt_pk_bf16(float lo, float hi) {
  unsigned int r;
  asm("v_cvt_pk_bf16_f32 %0, %1, %2" : "=v"(r) : "v"(lo), "v"(hi));
  return r;
}

// ---------------------------------------------------------------------------
// Prep: WCT2[(kq*512 + (o*8+kb))*8 + i] = bf16(wc[i][kb]) for (o, n_in=kq).
// k-dim index = n_in*8 + i, so kq = k/8, i = k%8. This layout makes the GEMM's
// B-fragment load one coalesced 16B global load per lane (L2-resident).
//       bias2[o*8+k] = bias[o,k] + (k==0)*bias_shift[o]
// ---------------------------------------------------------------------------
__global__ void clifford_prep(const float* __restrict__ weight,
                              const float* __restrict__ bias,
                              const float* __restrict__ row_scale,
                              const float* __restrict__ col_scale,
                              const float* __restrict__ bias_shift,
                              unsigned short* __restrict__ WCT2,
                              float* __restrict__ bias2) {
  const int t = blockIdx.x * 256 + threadIdx.x;
  if (t < 512) {
    const int o = t >> 3, k = t & 7;
    bias2[t] = bias[t] + (k == 0 ? bias_shift[o] : 0.0f);
  }
  if (t >= 64 * 64) return;
  const int o = t >> 6, n = t & 63;  // n = input feature = kq
  const float rs = row_scale[o], cs = col_scale[n];
  float w[8];
#pragma unroll
  for (int j = 0; j < 8; ++j) {
    float v = weight[(size_t)t * 8 + j] * rs * cs;
    w[j] = (v != v) ? 0.0f : v;  // nan_to_num
  }
  constexpr int TI[64] = {0,1,2,3,4,5,6,7, 0,1,2,4,3,5,6,7, 0,2,1,4,3,6,5,7,
                          0,3,1,5,2,6,4,7, 0,4,1,2,3,7,5,6, 0,5,1,3,2,7,4,6,
                          0,6,2,3,1,7,4,5, 0,7,1,6,2,5,3,4};
  constexpr int TJ[64] = {0,1,2,3,4,5,6,7, 1,0,4,2,5,3,7,6, 2,0,4,1,6,3,7,5,
                          3,0,5,1,6,2,7,4, 4,0,2,1,7,3,6,5, 5,0,3,1,7,2,6,4,
                          6,0,3,2,7,1,5,4, 7,0,6,1,5,2,4,3};
  constexpr int TK[64] = {0,0,0,0,0,0,0,0, 1,1,1,1,1,1,1,1, 2,2,2,2,2,2,2,2,
                          3,3,3,3,3,3,3,3, 4,4,4,4,4,4,4,4, 5,5,5,5,5,5,5,5,
                          6,6,6,6,6,6,6,6, 7,7,7,7,7,7,7,7};
  constexpr float TS[64] = {1,1,1,1,-1,-1,-1,-1, 1,1,-1,1,-1,1,-1,-1, 1,1,1,-1,-1,1,1,1,
                            1,1,1,-1,1,-1,-1,-1, 1,1,1,-1,1,1,-1,1,  1,1,1,-1,-1,-1,1,-1,
                            1,1,1,-1,1,1,-1,1,   1,1,1,1,-1,-1,1,1};
  float wc[8][8];
#pragma unroll
  for (int i = 0; i < 8; ++i)
#pragma unroll
    for (int k = 0; k < 8; ++k) wc[i][k] = 0.0f;
#pragma unroll
  for (int e = 0; e < 64; ++e) wc[TI[e]][TK[e]] += TS[e] * w[TJ[e]];
  // WCT2 layout: [kq=n][nOut=o*8+kb][i]
#pragma unroll
  for (int kb = 0; kb < 8; ++kb)
#pragma unroll
    for (int i = 0; i < 8; ++i)
      WCT2[((size_t)n * N_DIM + o * 8 + kb) * 8 + i] = f2bf(wc[i][kb]);
}

// ---------------------------------------------------------------------------
// GEMM: out[M,N] = x[M,K] * W^T (+ bias2). A staged via LDS (f32->bf16 with
// v_cvt_pk_bf16_f32), conflict-free k-group-major LDS layout [kg][row][8].
// B read DIRECTLY from L2-resident WCT2 (512 KB) into VGPRs, double-buffered
// -- no B LDS, no async-copy drain. One __syncthreads per k-step (A dbuf).
// XCD swizzle keeps the 4 n-tiles of an m-tile on one XCD for x L2 reuse.
// ---------------------------------------------------------------------------
__global__ __launch_bounds__(256) void clifford_gemm(
    const float* __restrict__ x, const unsigned short* __restrict__ WCT2,
    const float* __restrict__ bias2, float* __restrict__ out) {
  __shared__ __align__(16) unsigned short As[2][BM * BK];  // 2 x 8 KB bf16

  const int tid = threadIdx.x;
  const int lane = tid & 63;
  const int wv = tid >> 6;

  const int bid = blockIdx.x;
  const int grp = bid >> 5, r = bid & 31;
  const size_t m0 = (size_t)(grp * 8 + (r & 7)) * BM;
  const int n0 = (r >> 3) * BN;

  // A register staging: thread t loads 16 consecutive floats of row t>>1
  const int s_row = tid >> 1;
  const int s_half = tid & 1;
  const float* ag = x + (m0 + s_row) * (size_t)K_DIM + s_half * 16;

  // fragment geometry (16x16x32: A[m=lane&15][k=(lane>>4)*8+j])
  const int wm = (wv & 1) * 64;
  const int wn = (wv >> 1) * 64;
  const int lm = lane & 15;
  const int kg = lane >> 4;  // 0..3

  // B per-lane base (elements). fragment ni at +ni*128; k-step at +4*N_DIM*8.
  const unsigned short* bg = WCT2 + ((size_t)kg * N_DIM + (n0 + wn + lm)) * 8;

  f32x4 ar[4];
  const f32x4 zero = {0.f, 0.f, 0.f, 0.f};
  f32x4 acc[4][4];
#pragma unroll
  for (int i = 0; i < 4; ++i)
#pragma unroll
    for (int j = 0; j < 4; ++j) acc[i][j] = zero;

  auto loadA = [&](int kc) {
#pragma unroll
    for (int j = 0; j < 4; ++j) ar[j] = *(const f32x4*)(ag + kc + j * 4);
  };
  // LDS layout: elem((kg)*BM + row)*8 + j  -> quarter-wave reads/writes hit
  // 16 consecutive 16B slots => bank-conflict-free ds_*_b128.
  auto writeA = [&](int b) {
    union { us8 v; unsigned int w[4]; } p0, p1;
    p0.w[0] = cvt_pk_bf16(ar[0][0], ar[0][1]);
    p0.w[1] = cvt_pk_bf16(ar[0][2], ar[0][3]);
    p0.w[2] = cvt_pk_bf16(ar[1][0], ar[1][1]);
    p0.w[3] = cvt_pk_bf16(ar[1][2], ar[1][3]);
    p1.w[0] = cvt_pk_bf16(ar[2][0], ar[2][1]);
    p1.w[1] = cvt_pk_bf16(ar[2][2], ar[2][3]);
    p1.w[2] = cvt_pk_bf16(ar[3][0], ar[3][1]);
    p1.w[3] = cvt_pk_bf16(ar[3][2], ar[3][3]);
    unsigned short* d0 = &As[b][((s_half * 2) * BM + s_row) * 8];
    unsigned short* d1 = &As[b][((s_half * 2 + 1) * BM + s_row) * 8];
    *(us8*)d0 = p0.v;
    *(us8*)d1 = p1.v;
  };
  auto loadB = [&](us8 (&bb)[4], int ks) {
    const unsigned short* p = bg + (size_t)ks * (4 * N_DIM * 8);
#pragma unroll
    for (int ni = 0; ni < 4; ++ni) bb[ni] = *(const us8*)(p + ni * 128);
  };

  us8 b0[4], b1[4];

  // prologue: stage k-step 0
  loadA(0);
  writeA(0);
  loadB(b0, 0);
  __syncthreads();

  auto body = [&](int ks, int pb, us8 (&bc)[4], us8 (&bn)[4]) {
    const bool last = (ks == KSTEPS - 1);
    if (!last) {
      loadA((ks + 1) * BK);  // in flight during MFMA below
      loadB(bn, ks + 1);     // L2 hit, lands well before next step's MFMA
    }
    bf16x8 af[4];
#pragma unroll
    for (int mi = 0; mi < 4; ++mi)
      af[mi] = __builtin_bit_cast(
          bf16x8, *(const us8*)&As[pb][((size_t)kg * BM + wm + mi * 16 + lm) * 8]);
#pragma unroll
    for (int mi = 0; mi < 4; ++mi)
#pragma unroll
      for (int ni = 0; ni < 4; ++ni)
        acc[mi][ni] = __builtin_amdgcn_mfma_f32_16x16x32_bf16(
            af[mi], __builtin_bit_cast(bf16x8, bc[ni]), acc[mi][ni], 0, 0, 0);
    if (!last) {
      writeA(pb ^ 1);   // compiler waits vmcnt on ar[] here
      __syncthreads();  // next step reads As[pb^1]
    }
  };

  // 2x-unrolled so B double-buffer indices are compile-time (no scratch)
  for (int ks2 = 0; ks2 < KSTEPS; ks2 += 2) {
    body(ks2, 0, b0, b1);
    body(ks2 + 1, 1, b1, b0);
  }

  // epilogue: C/D layout col=lane&15 (n), row=(lane>>4)*4+reg (m)
#pragma unroll
  for (int ni = 0; ni < 4; ++ni) {
    const int nn = n0 + wn + ni * 16 + lm;
    const float b2 = bias2[nn];
#pragma unroll
    for (int mi = 0; mi < 4; ++mi) {
#pragma unroll
      for (int rr = 0; rr < 4; ++rr) {
        const size_t mm = m0 + wm + mi * 16 + kg * 4 + rr;
        out[mm * N_DIM + nn] = acc[mi][ni][rr] + b2;
      }
    }
  }
}

extern "C" void kernel_launch(void* const* d_in, const int* in_sizes, int n_in,
                              void* d_out, int out_size, void* d_ws, size_t ws_size,
                              hipStream_t stream) {
  const float* x          = (const float*)d_in[0];
  const float* weight     = (const float*)d_in[1];
  const float* bias       = (const float*)d_in[2];
  const float* row_scale  = (const float*)d_in[3];
  const float* col_scale  = (const float*)d_in[4];
  const float* bias_shift = (const float*)d_in[5];

  unsigned short* WCT2 = (unsigned short*)d_ws;                      // 512*512*2 B
  float* bias2 = (float*)((char*)d_ws + (size_t)N_DIM * K_DIM * 2);  // +2 KB

  clifford_prep<<<16, 256, 0, stream>>>(weight, bias, row_scale, col_scale,
                                        bias_shift, WCT2, bias2);
  clifford_gemm<<<(M_DIM / BM) * (N_DIM / BN), 256, 0, stream>>>(
      x, WCT2, bias2, (float*)d_out);
}